// Round 5
// baseline (424.752 us; speedup 1.0000x reference)
//
// r16 — r15's cross-tile pipeline, spill-proofed.
// r15 post-mortem: theory OK (serial-sum of pipes = 70us ≈ measured wall;
// convoy confirmed), implementation spilled: xf[8] live across 3 barrier
// phases + unrolled tile loop (SGPR 112) -> +166MB scratch traffic, 113us.
// r16 changes vs r15:
//  - next-tile obs+mask loads issued at TOP of L3 phase, LDS-written at END
//    of SAME phase (one-phase liveness; no reg crosses a barrier)
//  - #pragma unroll 1 tile loop, runtime-swapped LDS pointers (no dup)
//  - r14's proven 256-thread partition (wave = 2rt x 4ct, 40 VGPR base)
// Buffers (2 needed): L1 reads cp writes np; L2 reads np writes cp; L3
// reads cp; stage(t+1) writes np; swap at tile end. Hazards all barrier-
// separated (trace in comments at each phase).
// Gates: FETCH ~72MB, WRITE ~41MB, VGPR<=88, SGPR<64. Predict 66 -> 50-60us.
// If >=63 with clean gates: one-phase cover insufficient -> hide W-stream next.
#include <hip/hip_runtime.h>

typedef __attribute__((ext_vector_type(8))) short short8;
typedef __attribute__((ext_vector_type(8))) unsigned short ushort8;
typedef __attribute__((ext_vector_type(4))) float f32x4;

#define MT 32            // batch rows per tile
#define TILES 2          // tiles per block (grid stays 1024 -> 4 blocks/CU)
#define STR 264          // bf16 elems per LDS row: 256 + 8 pad (528B, 16B-aligned)

__device__ __forceinline__ float bmax_r16() { return __uint_as_float(0x7F7F0000u); }

// plain RTNE fp32 -> bf16 bits (pre-epilogue values provably finite/small).
__device__ __forceinline__ unsigned short f2bf_r16(float f) {
    unsigned int u = __float_as_uint(f);
    return (unsigned short)((u + 0x7fffu + ((u >> 16) & 1u)) >> 16);
}

// pack: one thread per 64-lane fragment slot; gathers 8 k-elements, ONE
// contiguous 16B write. dst[(frag*64+lane)*8+j], frag=(n>>4)*8+(k>>5),
// lane=((k>>3)&3)*16+(n&15), j=k&7.
__global__ __launch_bounds__(256)
void pack_weights_r16(const float* __restrict__ W1,
                      const float* __restrict__ W2,
                      const float* __restrict__ W3,
                      unsigned short* __restrict__ ws) {
    int s = blockIdx.x * 256 + threadIdx.x;     // 80 x 256 = 20480 slots
    const float* src;
    unsigned short* dst;
    int N;
    if (s < 8192)       { src = W1; dst = ws;          N = 256; }
    else if (s < 16384) { src = W2; dst = ws + 65536;  N = 256; s -= 8192; }
    else                { src = W3; dst = ws + 131072; N = 128; s -= 16384; }
    int frag = s >> 6, lane = s & 63;
    int kb = (frag & 7) * 32 + (lane >> 4) * 8;   // k base (8 consecutive k)
    int n  = (frag >> 3) * 16 + (lane & 15);
    ushort8 o;
    #pragma unroll
    for (int j = 0; j < 8; ++j) o[j] = f2bf_r16(src[(kb + j) * N + n]);
    *(ushort8*)&dst[s * 8] = o;
}

// One 32x256 dense layer (K=256): wave w owns col-tiles 4w..4w+3, all 32 rows.
__device__ __forceinline__ void layer_mfma_r16(
    const unsigned short* __restrict__ src, const unsigned short* __restrict__ wp,
    int wave, int lane, int quad, int noff, f32x4 acc[2][4])
{
    #pragma unroll
    for (int k0 = 0; k0 < 8; ++k0) {
        short8 b[4];
        #pragma unroll
        for (int ct = 0; ct < 4; ++ct)
            b[ct] = *(const short8*)&wp[(((wave * 4 + ct) * 8 + k0) * 64 + lane) * 8];
        #pragma unroll
        for (int rt = 0; rt < 2; ++rt) {
            short8 a = *(const short8*)&src[(rt * 16 + noff) * STR + k0 * 32 + quad * 8];
            #pragma unroll
            for (int ct = 0; ct < 4; ++ct)
                acc[rt][ct] = __builtin_amdgcn_mfma_f32_16x16x32_bf16(a, b[ct], acc[rt][ct], 0, 0, 0);
        }
    }
}

// bias+relu+cvt, store to the OTHER buffer (no intra-layer barrier needed).
__device__ __forceinline__ void layer_store_r16(
    unsigned short* __restrict__ dst, const float* __restrict__ bias,
    int wave, int quad, int noff, f32x4 acc[2][4])
{
    #pragma unroll
    for (int ct = 0; ct < 4; ++ct) {
        int col = (wave * 4 + ct) * 16 + noff;
        float bv = bias[col];
        #pragma unroll
        for (int rt = 0; rt < 2; ++rt) {
            #pragma unroll
            for (int i = 0; i < 4; ++i) {
                float v = fmaxf(acc[rt][ct][i] + bv, 0.0f);   // relu; finite by data
                dst[(rt * 16 + quad * 4 + i) * STR + col] = f2bf_r16(v);
            }
        }
    }
}

// cvt fp32 regs -> bf16, write to act buffer (2048 float4/tile, 8/thread).
__device__ __forceinline__ void stage_from_regs_r16(
    unsigned short* __restrict__ dst, const float4* v, int tid)
{
    #pragma unroll
    for (int i = 0; i < 8; ++i) {
        int f = tid + i * 256;        // 64 float4-chunks per row
        int row = f >> 6;
        int c4 = f & 63;
        ushort4 p;
        p.x = f2bf_r16(v[i].x); p.y = f2bf_r16(v[i].y);
        p.z = f2bf_r16(v[i].z); p.w = f2bf_r16(v[i].w);
        *(ushort4*)&dst[row * STR + c4 * 4] = p;
    }
}

__global__ __launch_bounds__(256, 4)   // 128-reg cap; LDS 34KB caps at 4 blocks/CU
void ColorNetwork_32495722561720_kernel(
        const float* __restrict__ obs,
        const int* __restrict__ amask,
        const float* __restrict__ b1,
        const float* __restrict__ b2,
        const float* __restrict__ b3,
        const unsigned short* __restrict__ w1p,
        const unsigned short* __restrict__ w2p,
        const unsigned short* __restrict__ w3p,
        float* __restrict__ out)
{
    __shared__ __align__(16) unsigned short actA[MT * STR];
    __shared__ __align__(16) unsigned short actB[MT * STR];
    __shared__ int rowanyA[MT];
    __shared__ int rowanyB[MT];

    const int tid  = threadIdx.x;
    const int wave = tid >> 6;
    const int lane = tid & 63;
    const int quad = lane >> 4;
    const int noff = lane & 15;
    const size_t row0 = (size_t)blockIdx.x * (MT * TILES);

    if (tid < MT) { rowanyA[tid] = 0; rowanyB[tid] = 0; }

    // ---- prologue: stage tile0 into actA (exposed; (TILES-1)/TILES hidden) ----
    {
        float4 xf[8];
        const float4* xin = (const float4*)(obs + row0 * 256);
        #pragma unroll
        for (int i = 0; i < 8; ++i) xf[i] = xin[tid + i * 256];
        __syncthreads();   // rowany zeros visible before ORs
        stage_from_regs_r16(actA, xf, tid);
        const int4* min4 = (const int4*)(amask + row0 * 128);
        #pragma unroll
        for (int i = 0; i < 4; ++i) {
            int f = tid + i * 256;
            int4 m = min4[f];
            if (m.x | m.y | m.z | m.w) rowanyA[f >> 5] = 1;   // benign race, all write 1
        }
    }
    __syncthreads();   // actA + rowanyA ready

    unsigned short* cp = actA;   // current buffer
    unsigned short* np = actB;   // other / next buffer
    int* rc = rowanyA;
    int* rn = rowanyB;

    #pragma unroll 1   // DO NOT unroll: r15's reg/SGPR bloat lesson
    for (int t = 0; t < TILES; ++t) {
        const size_t rowbase = row0 + (size_t)t * MT;
        const bool more = (t + 1 < TILES);

        {   // ---- layer 1: read cp -> write np ----
            // np last read by L2(t-1) [tile-end bar]; last written stage(t)
            // in L3-window(t-1) [same bar].
            f32x4 acc[2][4] = {};
            layer_mfma_r16(cp, w1p, wave, lane, quad, noff, acc);
            layer_store_r16(np, b1, wave, quad, noff, acc);
        }
        __syncthreads();

        // zero rn for t+1: its t-1 readers (L3(t-1) epi) are 2 bars back;
        // its OR-writers are in L3-window(t), 1 bar ahead (L2-end bar).
        if (more && tid < MT) rn[tid] = 0;

        {   // ---- layer 2: read np -> write cp (cp last read by L1, 1 bar) ----
            f32x4 acc[2][4] = {};
            layer_mfma_r16(np, w2p, wave, lane, quad, noff, acc);
            layer_store_r16(cp, b2, wave, quad, noff, acc);
        }
        __syncthreads();

        {   // ---- L3 phase: MFMA(cp) + stage(t+1)->np + epilogue, one phase ----
            // one-phase liveness: xf/mf live ONLY here (no barrier crossing).
            float4 xf[8];
            int4 mf[4];
            if (more) {
                const float4* xin = (const float4*)(obs + (rowbase + MT) * 256);
                #pragma unroll
                for (int i = 0; i < 8; ++i) xf[i] = xin[tid + i * 256];
                const int4* mn = (const int4*)(amask + (rowbase + MT) * 128);
                #pragma unroll
                for (int i = 0; i < 4; ++i) mf[i] = mn[tid + i * 256];
            }

            // L3 GEMM (N=128): wave owns 2 col-tiles
            f32x4 acc[2][2] = {};
            #pragma unroll
            for (int k0 = 0; k0 < 8; ++k0) {
                short8 b0 = *(const short8*)&w3p[(((wave * 2 + 0) * 8 + k0) * 64 + lane) * 8];
                short8 b1v = *(const short8*)&w3p[(((wave * 2 + 1) * 8 + k0) * 64 + lane) * 8];
                #pragma unroll
                for (int rt = 0; rt < 2; ++rt) {
                    short8 a = *(const short8*)&cp[(rt * 16 + noff) * STR + k0 * 32 + quad * 8];
                    acc[rt][0] = __builtin_amdgcn_mfma_f32_16x16x32_bf16(a, b0, acc[rt][0], 0, 0, 0);
                    acc[rt][1] = __builtin_amdgcn_mfma_f32_16x16x32_bf16(a, b1v, acc[rt][1], 0, 0, 0);
                }
            }

            if (more) {   // LDS writes land under the epilogue's global traffic
                stage_from_regs_r16(np, xf, tid);   // np: L2(t) read it, 1 bar back
                #pragma unroll
                for (int i = 0; i < 4; ++i) {
                    int f = tid + i * 256;
                    if (mf[i].x | mf[i].y | mf[i].z | mf[i].w) rn[f >> 5] = 1;
                }
            }

            // epilogue: masked fp32 store (mask words L2-hot from rowany pass)
            const float BM = bmax_r16();
            #pragma unroll
            for (int ct = 0; ct < 2; ++ct) {
                int col = (wave * 2 + ct) * 16 + noff;
                float bv = b3[col];
                #pragma unroll
                for (int rt = 0; rt < 2; ++rt) {
                    #pragma unroll
                    for (int i = 0; i < 4; ++i) {
                        int row = rt * 16 + quad * 4 + i;
                        int m = amask[(rowbase + row) * 128 + col];
                        float v = acc[rt][ct][i] + bv;
                        v = fminf(fmaxf(v, -BM), BM);        // finite AND bf16-finite
                        if (!(v == v)) v = 0.0f;             // NaN scrub (paranoia)
                        if (!m) v = -BM;                     // FLOAT_MIN stand-in
                        if (!rc[row]) v = (col == 0) ? 1.0f : -BM;
                        out[(rowbase + row) * 128 + col] = v;
                    }
                }
            }
        }
        __syncthreads();   // tile boundary: staged np/rn ready; cp reads done

        // swap buffers for next tile
        unsigned short* tp = cp; cp = np; np = tp;
        int* tr = rc; rc = rn; rn = tr;
    }
}

extern "C" void kernel_launch(void* const* d_in, const int* in_sizes, int n_in,
                              void* d_out, int out_size, void* d_ws, size_t ws_size,
                              hipStream_t stream) {
    const float* obs   = (const float*)d_in[0];
    const int*   amask = (const int*)d_in[1];
    const float* W1 = (const float*)d_in[2];
    const float* b1 = (const float*)d_in[3];
    const float* W2 = (const float*)d_in[4];
    const float* b2 = (const float*)d_in[5];
    const float* W3 = (const float*)d_in[6];
    const float* b3 = (const float*)d_in[7];
    float* out = (float*)d_out;

    const int B = in_sizes[0] / 256;   // 65536 batch rows

    unsigned short* ws = (unsigned short*)d_ws;    // 163840 bf16 = 320 KB packed
    unsigned short* w1p = ws;
    unsigned short* w2p = ws + 65536;
    unsigned short* w3p = ws + 131072;

    pack_weights_r16<<<80, 256, 0, stream>>>(W1, W2, W3, ws);

    ColorNetwork_32495722561720_kernel<<<B / (MT * TILES), 256, 0, stream>>>(
        obs, amask, b1, b2, b3, w1p, w2p, w3p, out);
}

// Round 6
// 184.631 us; speedup vs baseline: 2.3005x; 2.3005x over previous
//
// r17 — zero-barrier wave-slab design.
// r15/r16 post-mortem: barrier-phase pipelining dies to the register
// allocator every time (r16: runtime-swapped generic LDS pointers -> acc
// spilled every k0 iter -> 860MB scratch, 338us). Convoy diagnosis stands:
// r11's wall ≈ serial sum of pipe times; pipes never overlap because all
// waves are barrier-coupled into the same phase sequence.
// r17 removes the coupling entirely:
//  - each WAVE owns a private 32-row slab in LDS + private rowany; computes
//    stage -> L1 -> L2 -> L3 end-to-end. ZERO __syncthreads in the kernel.
//  - in-place slab is safe: wave holds all its A-fragments (64 VGPR) in
//    regs before overwriting; within-wave LDS ordering is guaranteed.
//  - 256 thr/block, 4 slabs = 68KB LDS -> 2 blocks/CU -> 2 waves/SIMD ->
//    256-reg budget vs ~120 peak: spills structurally impossible.
//  - ALL LDS accesses index the shared symbol directly (r16 lesson: never
//    runtime LDS pointers).
//  - 512 blocks, MT=128/block: balanced 2-blocks-per-CU dispatch.
// Gates: FETCH 60-80MB, WRITE ~41MB, VGPR<=~170. Occupancy ~25% BY DESIGN.
// Predict: dur 66 -> 35-48us, MfmaUtil 25-35%. If ~66 w/ clean gates:
// convoy theory falsified -> W-load latency next (explicit prefetch).
#include <hip/hip_runtime.h>

typedef __attribute__((ext_vector_type(8))) short short8;
typedef __attribute__((ext_vector_type(8))) unsigned short ushort8;
typedef __attribute__((ext_vector_type(4))) float f32x4;

#define MT 32            // batch rows per WAVE
#define NWAVE 4          // waves per block
#define STR 264          // bf16 elems per slab row: 256 + 8 pad (528B)

__device__ __forceinline__ float bmax_r17() { return __uint_as_float(0x7F7F0000u); }

// plain RTNE fp32 -> bf16 bits (pre-epilogue values provably finite/small).
__device__ __forceinline__ unsigned short f2bf_r17(float f) {
    unsigned int u = __float_as_uint(f);
    return (unsigned short)((u + 0x7fffu + ((u >> 16) & 1u)) >> 16);
}

// pack (unchanged, proven): one thread per 64-lane fragment slot.
// dst[(frag*64+lane)*8+j], frag=(n>>4)*8+(k>>5), lane=((k>>3)&3)*16+(n&15), j=k&7.
__global__ __launch_bounds__(256)
void pack_weights_r17(const float* __restrict__ W1,
                      const float* __restrict__ W2,
                      const float* __restrict__ W3,
                      unsigned short* __restrict__ ws) {
    int s = blockIdx.x * 256 + threadIdx.x;     // 80 x 256 = 20480 slots
    const float* src;
    unsigned short* dst;
    int N;
    if (s < 8192)       { src = W1; dst = ws;          N = 256; }
    else if (s < 16384) { src = W2; dst = ws + 65536;  N = 256; s -= 8192; }
    else                { src = W3; dst = ws + 131072; N = 128; s -= 16384; }
    int frag = s >> 6, lane = s & 63;
    int kb = (frag & 7) * 32 + (lane >> 4) * 8;   // k base (8 consecutive k)
    int n  = (frag >> 3) * 16 + (lane & 15);
    ushort8 o;
    #pragma unroll
    for (int j = 0; j < 8; ++j) o[j] = f2bf_r17(src[(kb + j) * N + n]);
    *(ushort8*)&dst[s * 8] = o;
}

__global__ __launch_bounds__(256, 2)   // 2 waves/SIMD -> 256-reg budget
void ColorNetwork_32495722561720_kernel(
        const float* __restrict__ obs,
        const int* __restrict__ amask,
        const float* __restrict__ b1,
        const float* __restrict__ b2,
        const float* __restrict__ b3,
        const unsigned short* __restrict__ w1p,
        const unsigned short* __restrict__ w2p,
        const unsigned short* __restrict__ w3p,
        float* __restrict__ out)
{
    // 4 x 16896B slabs + 4x32 rowany = 68096 B -> 2 blocks/CU
    __shared__ __align__(16) unsigned short act[NWAVE * MT * STR];
    __shared__ int rowany[NWAVE * MT];

    const int tid  = threadIdx.x;
    const int wave = tid >> 6;
    const int lane = tid & 63;
    const int quad = lane >> 4;
    const int noff = lane & 15;
    const int sb   = wave * (MT * STR);   // this wave's slab base (elements)
    const int rb   = wave * MT;           // this wave's rowany base
    const size_t rowbase = (size_t)blockIdx.x * (MT * NWAVE) + (size_t)wave * MT;

    // ---- stage: 32 rows x 256 fp32 -> bf16 slab (2048 float4, 32/lane) ----
    {
        const float4* xin = (const float4*)(obs + rowbase * 256);
        #pragma unroll 8
        for (int i = 0; i < 32; ++i) {
            int f = i * 64 + lane;          // 64 float4-chunks per row
            int row = f >> 6;
            int c4 = f & 63;
            float4 v = xin[f];
            ushort4 p;
            p.x = f2bf_r17(v.x); p.y = f2bf_r17(v.y);
            p.z = f2bf_r17(v.z); p.w = f2bf_r17(v.w);
            *(ushort4*)&act[sb + row * STR + c4 * 4] = p;
        }
    }

    // ---- rowany (wave-private; within-wave LDS ordering is guaranteed) ----
    if (lane < MT) rowany[rb + lane] = 0;
    {
        const int4* min4 = (const int4*)(amask + rowbase * 128);
        #pragma unroll 4
        for (int i = 0; i < 16; ++i) {
            int f = i * 64 + lane;          // 32 int4 per row
            int4 m = min4[f];
            if (m.x | m.y | m.z | m.w) rowany[rb + (f >> 5)] = 1;  // same-wave race: all write 1
        }
    }

    // A-fragment register slab: a[rt][k0] = 8 bf16 (64 VGPRs total).
    short8 a[2][8];

    // ---- layer 1: slab -> regs -> MFMA(w1p) -> relu -> slab (in place) ----
    #pragma unroll
    for (int rt = 0; rt < 2; ++rt)
        #pragma unroll
        for (int k0 = 0; k0 < 8; ++k0)
            a[rt][k0] = *(const short8*)&act[sb + (rt * 16 + noff) * STR + k0 * 32 + quad * 8];
    #pragma unroll 2
    for (int ct = 0; ct < 16; ++ct) {
        f32x4 ac0 = {}, ac1 = {};
        #pragma unroll
        for (int k0 = 0; k0 < 8; ++k0) {
            short8 b = *(const short8*)&w1p[((ct * 8 + k0) * 64 + lane) * 8];
            ac0 = __builtin_amdgcn_mfma_f32_16x16x32_bf16(a[0][k0], b, ac0, 0, 0, 0);
            ac1 = __builtin_amdgcn_mfma_f32_16x16x32_bf16(a[1][k0], b, ac1, 0, 0, 0);
        }
        int col = ct * 16 + noff;
        float bv = b1[col];
        #pragma unroll
        for (int i = 0; i < 4; ++i) {
            act[sb + (quad * 4 + i) * STR + col]      = f2bf_r17(fmaxf(ac0[i] + bv, 0.0f));
            act[sb + (16 + quad * 4 + i) * STR + col] = f2bf_r17(fmaxf(ac1[i] + bv, 0.0f));
        }
    }

    // ---- layer 2: same, with w2p ----
    #pragma unroll
    for (int rt = 0; rt < 2; ++rt)
        #pragma unroll
        for (int k0 = 0; k0 < 8; ++k0)
            a[rt][k0] = *(const short8*)&act[sb + (rt * 16 + noff) * STR + k0 * 32 + quad * 8];
    #pragma unroll 2
    for (int ct = 0; ct < 16; ++ct) {
        f32x4 ac0 = {}, ac1 = {};
        #pragma unroll
        for (int k0 = 0; k0 < 8; ++k0) {
            short8 b = *(const short8*)&w2p[((ct * 8 + k0) * 64 + lane) * 8];
            ac0 = __builtin_amdgcn_mfma_f32_16x16x32_bf16(a[0][k0], b, ac0, 0, 0, 0);
            ac1 = __builtin_amdgcn_mfma_f32_16x16x32_bf16(a[1][k0], b, ac1, 0, 0, 0);
        }
        int col = ct * 16 + noff;
        float bv = b2[col];
        #pragma unroll
        for (int i = 0; i < 4; ++i) {
            act[sb + (quad * 4 + i) * STR + col]      = f2bf_r17(fmaxf(ac0[i] + bv, 0.0f));
            act[sb + (16 + quad * 4 + i) * STR + col] = f2bf_r17(fmaxf(ac1[i] + bv, 0.0f));
        }
    }

    // ---- layer 3 (N=128): slab -> regs -> MFMA(w3p) -> masked fp32 store ----
    #pragma unroll
    for (int rt = 0; rt < 2; ++rt)
        #pragma unroll
        for (int k0 = 0; k0 < 8; ++k0)
            a[rt][k0] = *(const short8*)&act[sb + (rt * 16 + noff) * STR + k0 * 32 + quad * 8];

    // cache this lane's 8 rowany flags (wave-private LDS, no barrier needed)
    int ra[8];
    #pragma unroll
    for (int rt = 0; rt < 2; ++rt)
        #pragma unroll
        for (int i = 0; i < 4; ++i)
            ra[rt * 4 + i] = rowany[rb + rt * 16 + quad * 4 + i];

    const float BM = bmax_r17();
    #pragma unroll 2
    for (int ct = 0; ct < 8; ++ct) {
        f32x4 ac0 = {}, ac1 = {};
        #pragma unroll
        for (int k0 = 0; k0 < 8; ++k0) {
            short8 b = *(const short8*)&w3p[((ct * 8 + k0) * 64 + lane) * 8];
            ac0 = __builtin_amdgcn_mfma_f32_16x16x32_bf16(a[0][k0], b, ac0, 0, 0, 0);
            ac1 = __builtin_amdgcn_mfma_f32_16x16x32_bf16(a[1][k0], b, ac1, 0, 0, 0);
        }
        int col = ct * 16 + noff;
        float bv = b3[col];
        #pragma unroll
        for (int rt = 0; rt < 2; ++rt) {
            const f32x4& ac = rt ? ac1 : ac0;
            #pragma unroll
            for (int i = 0; i < 4; ++i) {
                int row = rt * 16 + quad * 4 + i;
                int m = amask[(rowbase + row) * 128 + col];   // L2-hot (rowany pass)
                float v = ac[i] + bv;
                v = fminf(fmaxf(v, -BM), BM);        // finite AND bf16-finite
                if (!(v == v)) v = 0.0f;             // NaN scrub (paranoia)
                if (!m) v = -BM;                     // FLOAT_MIN stand-in
                if (!ra[rt * 4 + i]) v = (col == 0) ? 1.0f : -BM;
                out[(rowbase + row) * 128 + col] = v;
            }
        }
    }
}

extern "C" void kernel_launch(void* const* d_in, const int* in_sizes, int n_in,
                              void* d_out, int out_size, void* d_ws, size_t ws_size,
                              hipStream_t stream) {
    const float* obs   = (const float*)d_in[0];
    const int*   amask = (const int*)d_in[1];
    const float* W1 = (const float*)d_in[2];
    const float* b1 = (const float*)d_in[3];
    const float* W2 = (const float*)d_in[4];
    const float* b2 = (const float*)d_in[5];
    const float* W3 = (const float*)d_in[6];
    const float* b3 = (const float*)d_in[7];
    float* out = (float*)d_out;

    const int B = in_sizes[0] / 256;   // 65536 batch rows

    unsigned short* ws = (unsigned short*)d_ws;    // 163840 bf16 = 320 KB packed
    unsigned short* w1p = ws;
    unsigned short* w2p = ws + 65536;
    unsigned short* w3p = ws + 131072;

    pack_weights_r17<<<80, 256, 0, stream>>>(W1, W2, W3, ws);

    ColorNetwork_32495722561720_kernel<<<B / (MT * NWAVE), 256, 0, stream>>>(
        obs, amask, b1, b2, b3, w1p, w2p, w3p, out);
}

// Round 7
// 165.816 us; speedup vs baseline: 2.5616x; 1.1135x over previous
//
// r18 — wave-slab TLP: 2-wave blocks, 9 slabs/CU, 18 waves/CU.
// r17 post-mortem (first clean experiment since r11): zero barriers + no
// spills = 80us at 8 waves/CU — WORSE than r11's 66 at ~15 waves/CU. Strong
// convoy theory falsified; refined model: dur ≈ per-wave dependency chain /
// overlapping waves. r17 starved TLP (17KB slab/wave -> LDS-capped).
// r18 gets decoupling AND waves:
//  - block = 128 thr (2 waves) sharing ONE 32-row slab, split by cols.
//    LDS 17KB/block -> 9 blocks/CU = 18 waves/CU, barrier domain = 2 waves,
//    9 de-phased blocks per CU -> no convoy.
//  - A-fragments reg-held per layer (32 VGPR, r17-proven) -> in-place slab
//    needs just 1 read->write barrier per layer (5 total, all 2-wave).
//  - B per wave 160KB -> 655MB L2 stream ~19us chip, overlapped by 18 waves.
//  - ~90 VGPR under (128,4)=128 cap: spill regime far away.
// Gates: FETCH 60-75MB, WRITE 33-41MB, VGPR<=110, LDS~17KB, Occ 45-56%.
// Predict: dur 66 -> 40-52us, MfmaUtil 18-25%. If ~66 w/ clean gates:
// per-ct B-load latency is the wall -> explicit prefetch depth next.
#include <hip/hip_runtime.h>

typedef __attribute__((ext_vector_type(8))) short short8;
typedef __attribute__((ext_vector_type(8))) unsigned short ushort8;
typedef __attribute__((ext_vector_type(4))) float f32x4;

#define MT 32            // batch rows per block (one slab)
#define STR 264          // bf16 elems per slab row: 256 + 8 pad (528B)

__device__ __forceinline__ float bmax_r18() { return __uint_as_float(0x7F7F0000u); }

// plain RTNE fp32 -> bf16 bits (pre-epilogue values provably finite/small).
__device__ __forceinline__ unsigned short f2bf_r18(float f) {
    unsigned int u = __float_as_uint(f);
    return (unsigned short)((u + 0x7fffu + ((u >> 16) & 1u)) >> 16);
}

// pack (unchanged, proven): one thread per 64-lane fragment slot.
// dst[(frag*64+lane)*8+j], frag=(n>>4)*8+(k>>5), lane=((k>>3)&3)*16+(n&15), j=k&7.
__global__ __launch_bounds__(256)
void pack_weights_r18(const float* __restrict__ W1,
                      const float* __restrict__ W2,
                      const float* __restrict__ W3,
                      unsigned short* __restrict__ ws) {
    int s = blockIdx.x * 256 + threadIdx.x;     // 80 x 256 = 20480 slots
    const float* src;
    unsigned short* dst;
    int N;
    if (s < 8192)       { src = W1; dst = ws;          N = 256; }
    else if (s < 16384) { src = W2; dst = ws + 65536;  N = 256; s -= 8192; }
    else                { src = W3; dst = ws + 131072; N = 128; s -= 16384; }
    int frag = s >> 6, lane = s & 63;
    int kb = (frag & 7) * 32 + (lane >> 4) * 8;   // k base (8 consecutive k)
    int n  = (frag >> 3) * 16 + (lane & 15);
    ushort8 o;
    #pragma unroll
    for (int j = 0; j < 8; ++j) o[j] = f2bf_r18(src[(kb + j) * N + n]);
    *(ushort8*)&dst[s * 8] = o;
}

__global__ __launch_bounds__(128, 4)   // 128-reg cap; LDS 17KB -> 9 blocks/CU
void ColorNetwork_32495722561720_kernel(
        const float* __restrict__ obs,
        const int* __restrict__ amask,
        const float* __restrict__ b1,
        const float* __restrict__ b2,
        const float* __restrict__ b3,
        const unsigned short* __restrict__ w1p,
        const unsigned short* __restrict__ w2p,
        const unsigned short* __restrict__ w3p,
        float* __restrict__ out)
{
    __shared__ __align__(16) unsigned short act[MT * STR];   // 16896 B
    __shared__ int rowany[MT];                               // 128 B

    const int tid  = threadIdx.x;
    const int wave = tid >> 6;          // 0..1 — owns cols [wave*128, +128)
    const int lane = tid & 63;
    const int quad = lane >> 4;
    const int noff = lane & 15;
    const size_t rowbase = (size_t)blockIdx.x * MT;

    if (tid < MT) rowany[tid] = 0;

    // ---- stage: 32 rows x 256 fp32 -> bf16 slab (2048 float4, 16/thread) ----
    {
        const float4* xin = (const float4*)(obs + rowbase * 256);
        #pragma unroll 4
        for (int i = 0; i < 16; ++i) {
            int f = tid + i * 128;          // 64 float4-chunks per row
            int row = f >> 6;
            int c4 = f & 63;
            float4 v = xin[f];
            ushort4 p;
            p.x = f2bf_r18(v.x); p.y = f2bf_r18(v.y);
            p.z = f2bf_r18(v.z); p.w = f2bf_r18(v.w);
            *(ushort4*)&act[row * STR + c4 * 4] = p;
        }
    }
    __syncthreads();   // slab visible to both waves; rowany zeros before ORs

    // ---- rowany: 32 rows x 32 int4, 8/thread (both waves OR; race benign) ----
    {
        const int4* min4 = (const int4*)(amask + rowbase * 128);
        #pragma unroll 4
        for (int i = 0; i < 8; ++i) {
            int f = tid + i * 128;          // 32 int4 per row
            int4 m = min4[f];
            if (m.x | m.y | m.z | m.w) rowany[f >> 5] = 1;
        }
    }

    short8 a[2][8];   // A-fragments of all 32 rows (held in regs per layer)

    // ================= layer 1: slab -> regs -> MFMA(w1p) -> slab =================
    #pragma unroll
    for (int rt = 0; rt < 2; ++rt)
        #pragma unroll
        for (int k0 = 0; k0 < 8; ++k0)
            a[rt][k0] = *(const short8*)&act[(rt * 16 + noff) * STR + k0 * 32 + quad * 8];
    __syncthreads();   // both waves' A-reads done -> in-place stores safe
                       // (also orders rowany ORs before epilogue reads)
    #pragma unroll 2
    for (int ct = 0; ct < 8; ++ct) {
        const int ctg = wave * 8 + ct;      // global col-tile 0..15
        f32x4 ac0 = {}, ac1 = {};
        #pragma unroll
        for (int k0 = 0; k0 < 8; ++k0) {
            short8 b = *(const short8*)&w1p[((ctg * 8 + k0) * 64 + lane) * 8];
            ac0 = __builtin_amdgcn_mfma_f32_16x16x32_bf16(a[0][k0], b, ac0, 0, 0, 0);
            ac1 = __builtin_amdgcn_mfma_f32_16x16x32_bf16(a[1][k0], b, ac1, 0, 0, 0);
        }
        const int col = ctg * 16 + noff;
        const float bv = b1[col];
        #pragma unroll
        for (int i = 0; i < 4; ++i) {
            act[(quad * 4 + i) * STR + col]      = f2bf_r18(fmaxf(ac0[i] + bv, 0.0f));
            act[(16 + quad * 4 + i) * STR + col] = f2bf_r18(fmaxf(ac1[i] + bv, 0.0f));
        }
    }
    __syncthreads();   // L1 writes visible

    // ================= layer 2: same with w2p =================
    #pragma unroll
    for (int rt = 0; rt < 2; ++rt)
        #pragma unroll
        for (int k0 = 0; k0 < 8; ++k0)
            a[rt][k0] = *(const short8*)&act[(rt * 16 + noff) * STR + k0 * 32 + quad * 8];
    __syncthreads();   // A-reads done -> stores safe
    #pragma unroll 2
    for (int ct = 0; ct < 8; ++ct) {
        const int ctg = wave * 8 + ct;
        f32x4 ac0 = {}, ac1 = {};
        #pragma unroll
        for (int k0 = 0; k0 < 8; ++k0) {
            short8 b = *(const short8*)&w2p[((ctg * 8 + k0) * 64 + lane) * 8];
            ac0 = __builtin_amdgcn_mfma_f32_16x16x32_bf16(a[0][k0], b, ac0, 0, 0, 0);
            ac1 = __builtin_amdgcn_mfma_f32_16x16x32_bf16(a[1][k0], b, ac1, 0, 0, 0);
        }
        const int col = ctg * 16 + noff;
        const float bv = b2[col];
        #pragma unroll
        for (int i = 0; i < 4; ++i) {
            act[(quad * 4 + i) * STR + col]      = f2bf_r18(fmaxf(ac0[i] + bv, 0.0f));
            act[(16 + quad * 4 + i) * STR + col] = f2bf_r18(fmaxf(ac1[i] + bv, 0.0f));
        }
    }
    __syncthreads();   // L2 writes visible

    // ================= layer 3 (N=128): no LDS stores -> no more barriers =================
    #pragma unroll
    for (int rt = 0; rt < 2; ++rt)
        #pragma unroll
        for (int k0 = 0; k0 < 8; ++k0)
            a[rt][k0] = *(const short8*)&act[(rt * 16 + noff) * STR + k0 * 32 + quad * 8];

    int ra[8];   // this lane's rowany flags (barriers since the ORs)
    #pragma unroll
    for (int rt = 0; rt < 2; ++rt)
        #pragma unroll
        for (int i = 0; i < 4; ++i)
            ra[rt * 4 + i] = rowany[rt * 16 + quad * 4 + i];

    const float BM = bmax_r18();
    #pragma unroll 2
    for (int ct = 0; ct < 4; ++ct) {
        const int ctg = wave * 4 + ct;      // global col-tile 0..7
        f32x4 ac0 = {}, ac1 = {};
        #pragma unroll
        for (int k0 = 0; k0 < 8; ++k0) {
            short8 b = *(const short8*)&w3p[((ctg * 8 + k0) * 64 + lane) * 8];
            ac0 = __builtin_amdgcn_mfma_f32_16x16x32_bf16(a[0][k0], b, ac0, 0, 0, 0);
            ac1 = __builtin_amdgcn_mfma_f32_16x16x32_bf16(a[1][k0], b, ac1, 0, 0, 0);
        }
        const int col = ctg * 16 + noff;
        const float bv = b3[col];
        #pragma unroll
        for (int rt = 0; rt < 2; ++rt) {
            const f32x4& ac = rt ? ac1 : ac0;
            #pragma unroll
            for (int i = 0; i < 4; ++i) {
                int row = rt * 16 + quad * 4 + i;
                int m = amask[(rowbase + row) * 128 + col];   // L2-hot (rowany pass)
                float v = ac[i] + bv;
                v = fminf(fmaxf(v, -BM), BM);        // finite AND bf16-finite
                if (!(v == v)) v = 0.0f;             // NaN scrub (paranoia)
                if (!m) v = -BM;                     // FLOAT_MIN stand-in
                if (!ra[rt * 4 + i]) v = (col == 0) ? 1.0f : -BM;
                out[(rowbase + row) * 128 + col] = v;
            }
        }
    }
}

extern "C" void kernel_launch(void* const* d_in, const int* in_sizes, int n_in,
                              void* d_out, int out_size, void* d_ws, size_t ws_size,
                              hipStream_t stream) {
    const float* obs   = (const float*)d_in[0];
    const int*   amask = (const int*)d_in[1];
    const float* W1 = (const float*)d_in[2];
    const float* b1 = (const float*)d_in[3];
    const float* W2 = (const float*)d_in[4];
    const float* b2 = (const float*)d_in[5];
    const float* W3 = (const float*)d_in[6];
    const float* b3 = (const float*)d_in[7];
    float* out = (float*)d_out;

    const int B = in_sizes[0] / 256;   // 65536 batch rows

    unsigned short* ws = (unsigned short*)d_ws;    // 163840 bf16 = 320 KB packed
    unsigned short* w1p = ws;
    unsigned short* w2p = ws + 65536;
    unsigned short* w3p = ws + 131072;

    pack_weights_r18<<<80, 256, 0, stream>>>(W1, W2, W3, ws);

    ColorNetwork_32495722561720_kernel<<<B / MT, 128, 0, stream>>>(
        obs, amask, b1, b2, b3, w1p, w2p, w3p, out);
}